// Round 6
// baseline (216.538 us; speedup 1.0000x reference)
//
#include <hip/hip_runtime.h>

// LinearAutoDecoder, LDS-resident bf16 weights, sequential X streaming.
// R5 post-mortem: binning fixed weight re-reads (210->173us) but randomized
// X row order + added 4 pre-kernels + gather/scatter overhead (~66us over the
// 107us HBM floor). This version keeps X perfectly sequential and holds ALL
// 192x319 weights in LDS as packed bf16 (147,456 B/block, 1 block/CU):
//   - pw dword d of (ch, lane l) packs bf16(w[ch][l+128d]) | bf16(w[ch][l+128d+64])<<16
//   - per row: 5 coalesced X loads, 3x 12B LDS reads, 15 FMA, DPP reduce.
// Accuracy: bf16 weights only (X and accum fp32): max err ~1e-2 << 0.169 thr.

constexpr int POS = 63;
constexpr int LAT = 256;
constexpr int DIM = 319;
constexpr int NCH = 192;                    // 3 * 64 clusters
constexpr int PW_DWORDS = NCH * 64 * 3;     // 36864 dwords
constexpr size_t PW_BYTES = (size_t)PW_DWORDS * 4;  // 147456 B

// ---------- RNE float -> bf16 bits ----------
__device__ __forceinline__ unsigned f2bf(float f) {
    unsigned u = __float_as_uint(f);
    return (u + 0x7fffu + ((u >> 16) & 1u)) >> 16;
}

// ---------- pack weights into ws ----------
__global__ __launch_bounds__(256) void pack_weights(
    const float* __restrict__ Wp,   // [192, 63]
    const float* __restrict__ Wf,   // [192, 256]
    unsigned* __restrict__ pw)
{
    const int idx = blockIdx.x * 256 + threadIdx.x;
    if (idx >= PW_DWORDS) return;
    const int ch  = idx / 192;          // 192 dwords per channel (64 lanes x 3)
    const int rem = idx - ch * 192;
    const int l   = rem / 3;
    const int d   = rem - l * 3;
    const int klo = l + 128 * d;
    const int khi = klo + 64;
    auto wat = [&](int k) -> float {
        if (k < POS) return Wp[ch * POS + k];
        if (k < DIM) return Wf[ch * LAT + (k - POS)];
        return 0.f;                      // pad (k >= 319)
    };
    pw[idx] = f2bf(wat(klo)) | (f2bf(wat(khi)) << 16);
}

// ---------- DPP wave64 sum (pure VALU), result valid in lane 63 ----------
template <int CTRL>
__device__ __forceinline__ float dpp_add_step(float x) {
    int s = __builtin_amdgcn_update_dpp(0, __float_as_int(x), CTRL,
                                        0xF, 0xF, /*bound_ctrl=*/true);
    return x + __int_as_float(s);
}
__device__ __forceinline__ float wave_reduce_sum(float x) {
    x = dpp_add_step<0x111>(x);  // row_shr:1
    x = dpp_add_step<0x112>(x);  // row_shr:2
    x = dpp_add_step<0x114>(x);  // row_shr:4
    x = dpp_add_step<0x118>(x);  // row_shr:8
    x = dpp_add_step<0x142>(x);  // row_bcast15
    x = dpp_add_step<0x143>(x);  // row_bcast31
    return x;
}

// ---------- main: 768 threads (12 waves), 1 block/CU, weights in LDS ----------
__global__ __launch_bounds__(768, 1) void lad_ldsw(
    const float* __restrict__ X,
    const int*   __restrict__ cid,
    const unsigned* __restrict__ pw,
    float*       __restrict__ out,
    int n)
{
    __shared__ unsigned wl[PW_DWORDS];   // 147,456 B

    // Stage packed weights (uint4-coalesced, one-time).
    {
        const uint4* src = (const uint4*)pw;
        uint4* dst = (uint4*)wl;
        for (int i = threadIdx.x; i < PW_DWORDS / 4; i += 768)
            dst[i] = src[i];
    }
    __syncthreads();

    const int l  = threadIdx.x & 63;
    const int wv = threadIdx.x >> 6;
    const int gw = blockIdx.x * 12 + wv;       // global wave id
    const int nw = gridDim.x * 12;             // total waves (3072)
    const int chunk = (n + nw - 1) / nw;       // contiguous rows per wave
    const int s = gw * chunk;
    const int e = min(s + chunk, n);

    auto body = [&](int r) {
        const int c3 = 3 * __builtin_amdgcn_readfirstlane(cid[r]);
        const float* xr = X + (size_t)r * DIM;
        const float x0 = xr[l];
        const float x1 = xr[l + 64];
        const float x2 = xr[l + 128];
        const float x3 = xr[l + 192];
        const float x4 = (l < 63) ? xr[l + 256] : 0.f;

        float acc[3];
#pragma unroll
        for (int j = 0; j < 3; ++j) {
            const unsigned* wp3 = &wl[(size_t)(c3 + j) * 192 + l * 3];
            const unsigned d0 = wp3[0], d1 = wp3[1], d2 = wp3[2];
            float a;
            a = x0 * __uint_as_float(d0 << 16);
            a = fmaf(x1, __uint_as_float(d0 & 0xffff0000u), a);
            a = fmaf(x2, __uint_as_float(d1 << 16), a);
            a = fmaf(x3, __uint_as_float(d1 & 0xffff0000u), a);
            a = fmaf(x4, __uint_as_float(d2 << 16), a);
            acc[j] = a;
        }
        const float r0 = wave_reduce_sum(acc[0]);
        const float r1 = wave_reduce_sum(acc[1]);
        const float r2 = wave_reduce_sum(acc[2]);
        if (l == 63) {
            float* o = out + (size_t)r * 3;
            o[0] = r0; o[1] = r1; o[2] = r2;
        }
    };

    // 2-row unroll for load/compute overlap.
    int r = s;
    for (; r + 2 <= e; r += 2) {
        body(r);
        body(r + 1);
    }
    if (r < e) body(r);
}

// ---------- fallback (R2 kernel) if workspace too small ----------
__global__ __launch_bounds__(256) void lad_fallback(
    const float* __restrict__ X,
    const int*   __restrict__ cid,
    const float* __restrict__ Wp,
    const float* __restrict__ Wf,
    float*       __restrict__ out,
    int n)
{
    const int lane = threadIdx.x & 63;
    const int wave = (int)((blockIdx.x * blockDim.x + threadIdx.x) >> 6);
    if (wave >= n) return;
    const size_t row = (size_t)wave;
    const float* xrow = X + row * (size_t)DIM;
    const float* xf   = xrow + POS;
    const int c3 = cid[row] * 3;
    const float* wp0 = Wp + (size_t)c3 * POS;
    const float* wf0 = Wf + (size_t)c3 * LAT;
    float a0 = 0.f, a1 = 0.f, a2 = 0.f;
#pragma unroll
    for (int i = 0; i < 4; ++i) {
        const int k = lane + 64 * i;
        const float x = xf[k];
        a0 = fmaf(x, wf0[k], a0);
        a1 = fmaf(x, wf0[k + LAT], a1);
        a2 = fmaf(x, wf0[k + 2 * LAT], a2);
    }
    if (lane < POS) {
        const float x = xrow[lane];
        a0 = fmaf(x, wp0[lane], a0);
        a1 = fmaf(x, wp0[lane + POS], a1);
        a2 = fmaf(x, wp0[lane + 2 * POS], a2);
    }
    a0 = wave_reduce_sum(a0);
    a1 = wave_reduce_sum(a1);
    a2 = wave_reduce_sum(a2);
    if (lane == 63) {
        float* o = out + row * 3;
        o[0] = a0; o[1] = a1; o[2] = a2;
    }
}

extern "C" void kernel_launch(void* const* d_in, const int* in_sizes, int n_in,
                              void* d_out, int out_size, void* d_ws, size_t ws_size,
                              hipStream_t stream) {
    const float* X   = (const float*)d_in[0];
    const int*   cid = (const int*)d_in[1];
    const float* Wp  = (const float*)d_in[2];
    const float* Wf  = (const float*)d_in[3];
    float* out = (float*)d_out;
    const int n = in_sizes[1];

    if (ws_size >= PW_BYTES) {
        unsigned* pw = (unsigned*)d_ws;
        pack_weights<<<(PW_DWORDS + 255) / 256, 256, 0, stream>>>(Wp, Wf, pw);
        lad_ldsw<<<256, 768, 0, stream>>>(X, cid, pw, out, n);
    } else {
        const int blocks = (n + 3) / 4;
        lad_fallback<<<blocks, 256, 0, stream>>>(X, cid, Wp, Wf, out, n);
    }
}

// Round 7
// 178.834 us; speedup vs baseline: 1.2108x; 1.2108x over previous
//
#include <hip/hip_runtime.h>

// LinearAutoDecoder, cluster-binned v2.
// R5 (173us) minus its overheads: cluster packed into perm (no cid gather in
// compute), depth-2 software pipeline (next row's X loads issued before the
// current row's FMA+reduce), nontemporal X. Weights live in 15 VGPRs per wave,
// reloaded only at cluster boundaries (~once per 64-row wave chunk).

constexpr int POS = 63;
constexpr int LAT = 256;
constexpr int DIM = 319;
constexpr int NCLUST = 64;
constexpr int WPAD = 320;        // padded weight row; wcat[ch][319] = 0
constexpr int HB = 256;          // histogram/scatter blocks

// ws layout: float wcat[192*320] | int hist[64] | int off[64] | uint perm[n]
constexpr size_t WCAT_ELEMS = (size_t)192 * WPAD;          // 61440 floats
constexpr size_t HIST_OFF = WCAT_ELEMS * 4;                // bytes
constexpr size_t OFF_OFF  = HIST_OFF + 64 * 4;
constexpr size_t PERM_OFF = OFF_OFF + 64 * 4;
static size_t ws_needed(int n) { return PERM_OFF + (size_t)n * 4; }

// ---------- init: padded concatenated weights + zero histogram ----------
__global__ __launch_bounds__(256) void init_wcat(
    const float* __restrict__ Wp,   // [192, 63]
    const float* __restrict__ Wf,   // [192, 256]
    float* __restrict__ wcat, int* __restrict__ hist)
{
    const int idx = blockIdx.x * 256 + threadIdx.x;
    if (idx < NCLUST) hist[idx] = 0;
    if (idx >= (int)WCAT_ELEMS) return;
    const int ch = idx / WPAD, k = idx % WPAD;
    float w = 0.f;
    if (k < POS)            w = Wp[ch * POS + k];
    else if (k < DIM)       w = Wf[ch * LAT + (k - POS)];
    wcat[idx] = w;
}

// ---------- histogram ----------
__global__ __launch_bounds__(256) void hist_kernel(
    const int* __restrict__ cid, int n, int* __restrict__ hist)
{
    __shared__ int h[NCLUST];
    const int t = threadIdx.x;
    if (t < NCLUST) h[t] = 0;
    __syncthreads();
    const int chunk = (n + HB - 1) / HB;
    const int lo = blockIdx.x * chunk;
    const int hi = min(lo + chunk, n);
    for (int i = lo + t; i < hi; i += 256)
        atomicAdd(&h[cid[i]], 1);
    __syncthreads();
    if (t < NCLUST) atomicAdd(&hist[t], h[t]);
}

// ---------- exclusive scan (64 bins) ----------
__global__ void scan_kernel(const int* __restrict__ hist, int* __restrict__ off)
{
    if (threadIdx.x == 0 && blockIdx.x == 0) {
        int acc = 0;
        for (int c = 0; c < NCLUST; ++c) { off[c] = acc; acc += hist[c]; }
    }
}

// ---------- scatter: perm[p] = (cluster << 24) | row ----------
__global__ __launch_bounds__(256) void scatter_kernel(
    const int* __restrict__ cid, int n, int* __restrict__ off,
    unsigned* __restrict__ perm)
{
    __shared__ int h[NCLUST];
    const int t = threadIdx.x;
    if (t < NCLUST) h[t] = 0;
    __syncthreads();
    const int chunk = (n + HB - 1) / HB;
    const int lo = blockIdx.x * chunk;
    const int hi = min(lo + chunk, n);
    for (int i = lo + t; i < hi; i += 256)
        atomicAdd(&h[cid[i]], 1);
    __syncthreads();
    if (t < NCLUST) h[t] = atomicAdd(&off[t], h[t]);  // reserve global range
    __syncthreads();
    for (int i = lo + t; i < hi; i += 256) {
        const int c = cid[i];
        const int p = atomicAdd(&h[c], 1);
        perm[p] = ((unsigned)c << 24) | (unsigned)i;
    }
}

// ---------- DPP wave64 sum (pure VALU), result valid in lane 63 ----------
template <int CTRL>
__device__ __forceinline__ float dpp_add_step(float x) {
    int s = __builtin_amdgcn_update_dpp(0, __float_as_int(x), CTRL,
                                        0xF, 0xF, /*bound_ctrl=*/true);
    return x + __int_as_float(s);
}
__device__ __forceinline__ float wave_reduce_sum(float x) {
    x = dpp_add_step<0x111>(x);  // row_shr:1
    x = dpp_add_step<0x112>(x);  // row_shr:2
    x = dpp_add_step<0x114>(x);  // row_shr:4
    x = dpp_add_step<0x118>(x);  // row_shr:8
    x = dpp_add_step<0x142>(x);  // row_bcast15
    x = dpp_add_step<0x143>(x);  // row_bcast31
    return x;
}

// ---------- main compute: one wave per 64 perm entries, depth-2 pipeline ----
__global__ __launch_bounds__(256) void lad_binned2(
    const float* __restrict__ X,
    const unsigned* __restrict__ perm,
    const float* __restrict__ wcat,
    float*       __restrict__ out,
    int n)
{
    const int l   = threadIdx.x & 63;
    const int wid = (int)((blockIdx.x * blockDim.x + threadIdx.x) >> 6);
    const int base = wid * 64;
    if (base >= n) return;

    unsigned vp = 0;
    if (base + l < n) vp = perm[base + l];
    const int cnt = min(64, n - base);

    // Prologue: unpack row 0, issue its X loads.
    unsigned pk = __builtin_amdgcn_readlane(vp, 0);
    int r_cur = (int)(pk & 0xFFFFFFu);
    int c_cur = (int)(pk >> 24);
    {
    }
    const float* xr0 = X + (size_t)r_cur * DIM + l;
    float xa0 = __builtin_nontemporal_load(xr0);
    float xa1 = __builtin_nontemporal_load(xr0 + 64);
    float xa2 = __builtin_nontemporal_load(xr0 + 128);
    float xa3 = __builtin_nontemporal_load(xr0 + 192);
    float xa4 = (l < 63) ? __builtin_nontemporal_load(xr0 + 256) : 0.f;

    int cur = -1;
    float w0[5], w1[5], w2[5];

    for (int j = 0; j < cnt; ++j) {
        // Issue next row's loads first (hidden under this row's compute).
        int r_nxt = 0, c_nxt = 0;
        float xb0 = 0.f, xb1 = 0.f, xb2 = 0.f, xb3 = 0.f, xb4 = 0.f;
        if (j + 1 < cnt) {
            const unsigned pkn = __builtin_amdgcn_readlane(vp, j + 1);
            r_nxt = (int)(pkn & 0xFFFFFFu);
            c_nxt = (int)(pkn >> 24);
            const float* xn = X + (size_t)r_nxt * DIM + l;
            xb0 = __builtin_nontemporal_load(xn);
            xb1 = __builtin_nontemporal_load(xn + 64);
            xb2 = __builtin_nontemporal_load(xn + 128);
            xb3 = __builtin_nontemporal_load(xn + 192);
            if (l < 63) xb4 = __builtin_nontemporal_load(xn + 256);
        }

        // Reload weights on cluster change (uniform branch, ~once per wave).
        if (c_cur != cur) {
            cur = c_cur;
            const float* wb = wcat + (size_t)(3 * cur) * WPAD + l;
#pragma unroll
            for (int i = 0; i < 5; ++i) {
                w0[i] = wb[i * 64];
                w1[i] = wb[WPAD + i * 64];
                w2[i] = wb[2 * WPAD + i * 64];
            }
        }

        float a0 = xa0 * w0[0];
        float a1 = xa0 * w1[0];
        float a2 = xa0 * w2[0];
        a0 = fmaf(xa1, w0[1], a0); a1 = fmaf(xa1, w1[1], a1); a2 = fmaf(xa1, w2[1], a2);
        a0 = fmaf(xa2, w0[2], a0); a1 = fmaf(xa2, w1[2], a1); a2 = fmaf(xa2, w2[2], a2);
        a0 = fmaf(xa3, w0[3], a0); a1 = fmaf(xa3, w1[3], a1); a2 = fmaf(xa3, w2[3], a2);
        a0 = fmaf(xa4, w0[4], a0); a1 = fmaf(xa4, w1[4], a1); a2 = fmaf(xa4, w2[4], a2);

        a0 = wave_reduce_sum(a0);
        a1 = wave_reduce_sum(a1);
        a2 = wave_reduce_sum(a2);
        if (l == 63) {
            float* o = out + (size_t)r_cur * 3;
            o[0] = a0; o[1] = a1; o[2] = a2;
        }

        r_cur = r_nxt; c_cur = c_nxt;
        xa0 = xb0; xa1 = xb1; xa2 = xb2; xa3 = xb3; xa4 = xb4;
    }
}

// ---------- fallback (R2 kernel) if workspace too small ----------
__global__ __launch_bounds__(256) void lad_fallback(
    const float* __restrict__ X,
    const int*   __restrict__ cid,
    const float* __restrict__ Wp,
    const float* __restrict__ Wf,
    float*       __restrict__ out,
    int n)
{
    const int lane = threadIdx.x & 63;
    const int wave = (int)((blockIdx.x * blockDim.x + threadIdx.x) >> 6);
    if (wave >= n) return;
    const size_t row = (size_t)wave;
    const float* xrow = X + row * (size_t)DIM;
    const float* xf   = xrow + POS;
    const int c3 = cid[row] * 3;
    const float* wp0 = Wp + (size_t)c3 * POS;
    const float* wf0 = Wf + (size_t)c3 * LAT;
    float a0 = 0.f, a1 = 0.f, a2 = 0.f;
#pragma unroll
    for (int i = 0; i < 4; ++i) {
        const int k = lane + 64 * i;
        const float x = xf[k];
        a0 = fmaf(x, wf0[k], a0);
        a1 = fmaf(x, wf0[k + LAT], a1);
        a2 = fmaf(x, wf0[k + 2 * LAT], a2);
    }
    if (lane < POS) {
        const float x = xrow[lane];
        a0 = fmaf(x, wp0[lane], a0);
        a1 = fmaf(x, wp0[lane + POS], a1);
        a2 = fmaf(x, wp0[lane + 2 * POS], a2);
    }
    a0 = wave_reduce_sum(a0);
    a1 = wave_reduce_sum(a1);
    a2 = wave_reduce_sum(a2);
    if (lane == 63) {
        float* o = out + row * 3;
        o[0] = a0; o[1] = a1; o[2] = a2;
    }
}

extern "C" void kernel_launch(void* const* d_in, const int* in_sizes, int n_in,
                              void* d_out, int out_size, void* d_ws, size_t ws_size,
                              hipStream_t stream) {
    const float* X   = (const float*)d_in[0];
    const int*   cid = (const int*)d_in[1];
    const float* Wp  = (const float*)d_in[2];
    const float* Wf  = (const float*)d_in[3];
    float* out = (float*)d_out;
    const int n = in_sizes[1];

    if (ws_size >= ws_needed(n)) {
        char* ws = (char*)d_ws;
        float*    wcat = (float*)ws;
        int*      hist = (int*)(ws + HIST_OFF);
        int*      off  = (int*)(ws + OFF_OFF);
        unsigned* perm = (unsigned*)(ws + PERM_OFF);

        const int init_blocks = ((int)WCAT_ELEMS + 255) / 256;  // 240
        init_wcat<<<init_blocks, 256, 0, stream>>>(Wp, Wf, wcat, hist);
        hist_kernel<<<HB, 256, 0, stream>>>(cid, n, hist);
        scan_kernel<<<1, 64, 0, stream>>>(hist, off);
        scatter_kernel<<<HB, 256, 0, stream>>>(cid, n, off, perm);

        const int waves = (n + 63) / 64;
        const int blocks = (waves + 3) / 4;
        lad_binned2<<<blocks, 256, 0, stream>>>(X, perm, wcat, out, n);
    } else {
        const int blocks = (n + 3) / 4;
        lad_fallback<<<blocks, 256, 0, stream>>>(X, cid, Wp, Wf, out, n);
    }
}

// Round 8
// 174.028 us; speedup vs baseline: 1.2443x; 1.0276x over previous
//
#include <hip/hip_runtime.h>

// LinearAutoDecoder R8: sequential X (fp32 dwords), bf16-packed weights.
// Model from R1-R7: CU vector-memory return path caps at ~12.6 TB/s aggregate;
// binned-random X caps DRAM at ~70%. Sequential X + halved weight bytes fits
// both: 3260 B/row through the L1 path -> ~132us byte-model.
// Weight pack: dword (ch, d, l) at pw[ch*192 + d*64 + l] holds
//   lo = bf16(w[ch][l+128d]), hi = bf16(w[ch][l+64+128d])   (0-padded past 318)
// which matches lane l's X registers x_d = X[row][l+128d], X[row][l+64+128d].

constexpr int POS = 63;
constexpr int LAT = 256;
constexpr int DIM = 319;
constexpr int NCH = 192;                       // 3 * 64 clusters
constexpr int PW_DWORDS = NCH * 192;           // 36864
constexpr size_t PW_BYTES = (size_t)PW_DWORDS * 4;

// ---------- RNE float -> bf16 bits ----------
__device__ __forceinline__ unsigned f2bf(float f) {
    unsigned u = __float_as_uint(f);
    return (u + 0x7fffu + ((u >> 16) & 1u)) >> 16;
}

// ---------- pack weights ----------
__global__ __launch_bounds__(256) void pack_weights(
    const float* __restrict__ Wp,   // [192, 63]
    const float* __restrict__ Wf,   // [192, 256]
    unsigned* __restrict__ pw)
{
    const int idx = blockIdx.x * 256 + threadIdx.x;
    if (idx >= PW_DWORDS) return;
    const int ch  = idx / 192;
    const int rem = idx - ch * 192;
    const int d   = rem >> 6;
    const int l   = rem & 63;
    const int klo = l + 128 * d;
    const int khi = klo + 64;
    auto wat = [&](int k) -> float {
        if (k < POS) return Wp[ch * POS + k];
        if (k < DIM) return Wf[ch * LAT + (k - POS)];
        return 0.f;
    };
    pw[idx] = f2bf(wat(klo)) | (f2bf(wat(khi)) << 16);
}

// ---------- DPP wave64 sum (pure VALU), result valid in lane 63 ----------
template <int CTRL>
__device__ __forceinline__ float dpp_add_step(float x) {
    int s = __builtin_amdgcn_update_dpp(0, __float_as_int(x), CTRL,
                                        0xF, 0xF, /*bound_ctrl=*/true);
    return x + __int_as_float(s);
}
__device__ __forceinline__ float wave_reduce_sum(float x) {
    x = dpp_add_step<0x111>(x);  // row_shr:1
    x = dpp_add_step<0x112>(x);  // row_shr:2
    x = dpp_add_step<0x114>(x);  // row_shr:4
    x = dpp_add_step<0x118>(x);  // row_shr:8
    x = dpp_add_step<0x142>(x);  // row_bcast15
    x = dpp_add_step<0x143>(x);  // row_bcast31
    return x;
}

__device__ __forceinline__ float blo(unsigned w) { return __uint_as_float(w << 16); }
__device__ __forceinline__ float bhi(unsigned w) { return __uint_as_float(w & 0xffff0000u); }

// ---------- main: one wave per row, sequential order ----------
__global__ __launch_bounds__(256) void lad_seq(
    const float* __restrict__ X,
    const int*   __restrict__ cid,
    const unsigned* __restrict__ pw,
    float*       __restrict__ out,
    int n)
{
    const int l    = threadIdx.x & 63;
    const int wave = (int)((blockIdx.x * blockDim.x + threadIdx.x) >> 6);
    if (wave >= n) return;

    const size_t row = (size_t)wave;
    const float* xr = X + row * (size_t)DIM;
    const int c3 = 3 * __builtin_amdgcn_readfirstlane(cid[row]);
    const unsigned* wb = pw + (size_t)c3 * 192;

    // X: 5 coalesced dword loads (k = l, l+64, l+128, l+192, l+256).
    const float x0 = xr[l];
    const float x1 = xr[l + 64];
    const float x2 = xr[l + 128];
    const float x3 = xr[l + 192];
    const float x4 = (l < 63) ? xr[l + 256] : 0.f;

    // Weights: 9 unit-stride dword loads (3 per channel), issued upfront.
    const unsigned wA0 = wb[l],       wA1 = wb[64 + l],  wA2 = wb[128 + l];
    const unsigned wB0 = wb[192 + l], wB1 = wb[256 + l], wB2 = wb[320 + l];
    const unsigned wC0 = wb[384 + l], wC1 = wb[448 + l], wC2 = wb[512 + l];

    float a0 = x0 * blo(wA0);
    a0 = fmaf(x1, bhi(wA0), a0);
    a0 = fmaf(x2, blo(wA1), a0);
    a0 = fmaf(x3, bhi(wA1), a0);
    a0 = fmaf(x4, blo(wA2), a0);

    float a1 = x0 * blo(wB0);
    a1 = fmaf(x1, bhi(wB0), a1);
    a1 = fmaf(x2, blo(wB1), a1);
    a1 = fmaf(x3, bhi(wB1), a1);
    a1 = fmaf(x4, blo(wB2), a1);

    float a2 = x0 * blo(wC0);
    a2 = fmaf(x1, bhi(wC0), a2);
    a2 = fmaf(x2, blo(wC1), a2);
    a2 = fmaf(x3, bhi(wC1), a2);
    a2 = fmaf(x4, blo(wC2), a2);

    a0 = wave_reduce_sum(a0);
    a1 = wave_reduce_sum(a1);
    a2 = wave_reduce_sum(a2);

    if (l == 63) {
        float* o = out + row * 3;
        o[0] = a0; o[1] = a1; o[2] = a2;
    }
}

// ---------- fallback (R2 kernel, fp32 weights) if workspace too small ------
__global__ __launch_bounds__(256) void lad_fallback(
    const float* __restrict__ X,
    const int*   __restrict__ cid,
    const float* __restrict__ Wp,
    const float* __restrict__ Wf,
    float*       __restrict__ out,
    int n)
{
    const int lane = threadIdx.x & 63;
    const int wave = (int)((blockIdx.x * blockDim.x + threadIdx.x) >> 6);
    if (wave >= n) return;
    const size_t row = (size_t)wave;
    const float* xrow = X + row * (size_t)DIM;
    const float* xf   = xrow + POS;
    const int c3 = cid[row] * 3;
    const float* wp0 = Wp + (size_t)c3 * POS;
    const float* wf0 = Wf + (size_t)c3 * LAT;
    float a0 = 0.f, a1 = 0.f, a2 = 0.f;
#pragma unroll
    for (int i = 0; i < 4; ++i) {
        const int k = lane + 64 * i;
        const float x = xf[k];
        a0 = fmaf(x, wf0[k], a0);
        a1 = fmaf(x, wf0[k + LAT], a1);
        a2 = fmaf(x, wf0[k + 2 * LAT], a2);
    }
    if (lane < POS) {
        const float x = xrow[lane];
        a0 = fmaf(x, wp0[lane], a0);
        a1 = fmaf(x, wp0[lane + POS], a1);
        a2 = fmaf(x, wp0[lane + 2 * POS], a2);
    }
    a0 = wave_reduce_sum(a0);
    a1 = wave_reduce_sum(a1);
    a2 = wave_reduce_sum(a2);
    if (lane == 63) {
        float* o = out + row * 3;
        o[0] = a0; o[1] = a1; o[2] = a2;
    }
}

extern "C" void kernel_launch(void* const* d_in, const int* in_sizes, int n_in,
                              void* d_out, int out_size, void* d_ws, size_t ws_size,
                              hipStream_t stream) {
    const float* X   = (const float*)d_in[0];
    const int*   cid = (const int*)d_in[1];
    const float* Wp  = (const float*)d_in[2];
    const float* Wf  = (const float*)d_in[3];
    float* out = (float*)d_out;
    const int n = in_sizes[1];

    if (ws_size >= PW_BYTES) {
        unsigned* pw = (unsigned*)d_ws;
        pack_weights<<<(PW_DWORDS + 255) / 256, 256, 0, stream>>>(Wp, Wf, pw);
        const int blocks = (n + 3) / 4;   // 4 waves (rows) per 256-thread block
        lad_seq<<<blocks, 256, 0, stream>>>(X, cid, pw, out, n);
    } else {
        const int blocks = (n + 3) / 4;
        lad_fallback<<<blocks, 256, 0, stream>>>(X, cid, Wp, Wf, out, n);
    }
}

// Round 9
// 168.631 us; speedup vs baseline: 1.2841x; 1.0320x over previous
//
#include <hip/hip_runtime.h>

// LinearAutoDecoder R9: weights in LDS (bf16), 16 waves/CU, depth-2 pipeline,
// chip-linear X walk.
// Model (R1-R8): all vector-path bytes (X from HBM + W from L2) drain at
// ~20 B/cyc/CU; W re-reads (2304 B/row) cost ~70us. Moving W to the DS pipe
// leaves only X (1280 B/row -> ~55 cyc/row << HBM share). R6 tried this and
// hit a latency wall (12 waves, no pipeline, ~15KB in flight < 22KB BWxLat);
// R9 fixes it: 16 waves + explicit depth-2 prefetch of {X, W-ds_read, cid}
// = ~41KB in flight, and iteration i processes rows [i*4096 + blk*16 + wave]
// so the entire chip reads X sequentially (DRAM-friendly, L3-friendly).

constexpr int POS = 63;
constexpr int LAT = 256;
constexpr int DIM = 319;
constexpr int NCH = 192;                        // 3 * 64 clusters
constexpr int PW_DWORDS = NCH * 192;            // 36864 dwords = 147,456 B
constexpr size_t PW_BYTES = (size_t)PW_DWORDS * 4;
constexpr int NBLK = 256;                       // 1 block per CU
constexpr int NW = 16;                          // waves per block
constexpr int STRIDE = NBLK * NW;               // 4096 rows per chip sweep

// ---------- RNE float -> bf16 bits ----------
__device__ __forceinline__ unsigned f2bf(float f) {
    unsigned u = __float_as_uint(f);
    return (u + 0x7fffu + ((u >> 16) & 1u)) >> 16;
}

// ---------- pack weights: dword (ch,l,d) at ch*192 + l*3 + d ----------
// packs bf16(w[ch][l+128d]) | bf16(w[ch][l+64+128d])<<16, 0 past 318.
// Lane l reads 3 consecutive dwords (12B) -> ds_read_b96, stride-3 banks
// (coprime with 32) -> conflict-free.
__global__ __launch_bounds__(256) void pack_weights(
    const float* __restrict__ Wp,   // [192, 63]
    const float* __restrict__ Wf,   // [192, 256]
    unsigned* __restrict__ pw)
{
    const int idx = blockIdx.x * 256 + threadIdx.x;
    if (idx >= PW_DWORDS) return;
    const int ch  = idx / 192;
    const int rem = idx - ch * 192;
    const int l   = rem / 3;
    const int d   = rem - l * 3;
    const int klo = l + 128 * d;
    const int khi = klo + 64;
    auto wat = [&](int k) -> float {
        if (k < POS) return Wp[ch * POS + k];
        if (k < DIM) return Wf[ch * LAT + (k - POS)];
        return 0.f;
    };
    pw[idx] = f2bf(wat(klo)) | (f2bf(wat(khi)) << 16);
}

// ---------- DPP wave64 sum (pure VALU), result valid in lane 63 ----------
template <int CTRL>
__device__ __forceinline__ float dpp_add_step(float x) {
    int s = __builtin_amdgcn_update_dpp(0, __float_as_int(x), CTRL,
                                        0xF, 0xF, /*bound_ctrl=*/true);
    return x + __int_as_float(s);
}
__device__ __forceinline__ float wave_reduce_sum(float x) {
    x = dpp_add_step<0x111>(x);  // row_shr:1
    x = dpp_add_step<0x112>(x);  // row_shr:2
    x = dpp_add_step<0x114>(x);  // row_shr:4
    x = dpp_add_step<0x118>(x);  // row_shr:8
    x = dpp_add_step<0x142>(x);  // row_bcast15
    x = dpp_add_step<0x143>(x);  // row_bcast31
    return x;
}

__device__ __forceinline__ float blo(unsigned w) { return __uint_as_float(w << 16); }
__device__ __forceinline__ float bhi(unsigned w) { return __uint_as_float(w & 0xffff0000u); }

// ---------- main: 1024 threads (16 waves), 1 block/CU, W in LDS ----------
__global__ __launch_bounds__(1024, 1) void lad_ldsw16(
    const float* __restrict__ X,
    const int*   __restrict__ cid,
    const unsigned* __restrict__ pw,
    float*       __restrict__ out,
    int n)
{
    __shared__ unsigned wl[PW_DWORDS];   // 147,456 B

    {   // one-time stage, uint4-coalesced
        const uint4* src = (const uint4*)pw;
        uint4* dst = (uint4*)wl;
        for (int i = threadIdx.x; i < PW_DWORDS / 4; i += 1024)
            dst[i] = src[i];
    }
    __syncthreads();

    const int l = threadIdx.x & 63;
    const int w = threadIdx.x >> 6;

    int r = blockIdx.x * NW + w;
    if (r >= n) return;

    // ---- prologue: row r fully prefetched ----
    int c_cur = 3 * __builtin_amdgcn_readfirstlane(cid[r]);
    {
    }
    const float* xr = X + (size_t)r * DIM;
    float xa0 = xr[l];
    float xa1 = xr[l + 64];
    float xa2 = xr[l + 128];
    float xa3 = xr[l + 192];
    float xa4 = (l < 63) ? xr[l + 256] : 0.f;

    unsigned aj0[3], aj1[3], aj2[3];
#pragma unroll
    for (int j = 0; j < 3; ++j) {
        const unsigned* p = &wl[(size_t)(c_cur + j) * 192 + l * 3];
        aj0[j] = p[0]; aj1[j] = p[1]; aj2[j] = p[2];
    }
    int c_nxt = (r + STRIDE < n)
        ? 3 * __builtin_amdgcn_readfirstlane(cid[r + STRIDE]) : 0;

    while (true) {
        const int r_nxt = r + STRIDE;
        const bool has_nxt = (r_nxt < n);

        // ---- prefetch row r_nxt: X globals, W ds_reads, cid for r_nxt+STRIDE
        float xb0 = 0.f, xb1 = 0.f, xb2 = 0.f, xb3 = 0.f, xb4 = 0.f;
        unsigned bj0[3], bj1[3], bj2[3];
        int c_nn = 0;
        if (has_nxt) {
            const float* xn = X + (size_t)r_nxt * DIM;
            xb0 = xn[l];
            xb1 = xn[l + 64];
            xb2 = xn[l + 128];
            xb3 = xn[l + 192];
            if (l < 63) xb4 = xn[l + 256];
#pragma unroll
            for (int j = 0; j < 3; ++j) {
                const unsigned* p = &wl[(size_t)(c_nxt + j) * 192 + l * 3];
                bj0[j] = p[0]; bj1[j] = p[1]; bj2[j] = p[2];
            }
            if (r_nxt + STRIDE < n)
                c_nn = 3 * __builtin_amdgcn_readfirstlane(cid[r_nxt + STRIDE]);
        } else {
            bj0[0]=bj0[1]=bj0[2]=bj1[0]=bj1[1]=bj1[2]=bj2[0]=bj2[1]=bj2[2]=0;
        }

        // ---- compute row r (all operands resident) ----
        float acc[3];
#pragma unroll
        for (int j = 0; j < 3; ++j) {
            float a = xa0 * blo(aj0[j]);
            a = fmaf(xa1, bhi(aj0[j]), a);
            a = fmaf(xa2, blo(aj1[j]), a);
            a = fmaf(xa3, bhi(aj1[j]), a);
            a = fmaf(xa4, blo(aj2[j]), a);
            acc[j] = a;
        }
        acc[0] = wave_reduce_sum(acc[0]);
        acc[1] = wave_reduce_sum(acc[1]);
        acc[2] = wave_reduce_sum(acc[2]);
        if (l == 63) {
            float* o = out + (size_t)r * 3;
            o[0] = acc[0]; o[1] = acc[1]; o[2] = acc[2];
        }

        if (!has_nxt) break;
        r = r_nxt; c_cur = c_nxt; c_nxt = c_nn;
        xa0 = xb0; xa1 = xb1; xa2 = xb2; xa3 = xb3; xa4 = xb4;
#pragma unroll
        for (int j = 0; j < 3; ++j) {
            aj0[j] = bj0[j]; aj1[j] = bj1[j]; aj2[j] = bj2[j];
        }
    }
}

// ---------- fallback (R2 kernel, fp32 weights) if workspace too small ------
__global__ __launch_bounds__(256) void lad_fallback(
    const float* __restrict__ X,
    const int*   __restrict__ cid,
    const float* __restrict__ Wp,
    const float* __restrict__ Wf,
    float*       __restrict__ out,
    int n)
{
    const int lane = threadIdx.x & 63;
    const int wave = (int)((blockIdx.x * blockDim.x + threadIdx.x) >> 6);
    if (wave >= n) return;
    const size_t row = (size_t)wave;
    const float* xrow = X + row * (size_t)DIM;
    const float* xf   = xrow + POS;
    const int c3 = cid[row] * 3;
    const float* wp0 = Wp + (size_t)c3 * POS;
    const float* wf0 = Wf + (size_t)c3 * LAT;
    float a0 = 0.f, a1 = 0.f, a2 = 0.f;
#pragma unroll
    for (int i = 0; i < 4; ++i) {
        const int k = lane + 64 * i;
        const float x = xf[k];
        a0 = fmaf(x, wf0[k], a0);
        a1 = fmaf(x, wf0[k + LAT], a1);
        a2 = fmaf(x, wf0[k + 2 * LAT], a2);
    }
    if (lane < POS) {
        const float x = xrow[lane];
        a0 = fmaf(x, wp0[lane], a0);
        a1 = fmaf(x, wp0[lane + POS], a1);
        a2 = fmaf(x, wp0[lane + 2 * POS], a2);
    }
    a0 = wave_reduce_sum(a0);
    a1 = wave_reduce_sum(a1);
    a2 = wave_reduce_sum(a2);
    if (lane == 63) {
        float* o = out + row * 3;
        o[0] = a0; o[1] = a1; o[2] = a2;
    }
}

extern "C" void kernel_launch(void* const* d_in, const int* in_sizes, int n_in,
                              void* d_out, int out_size, void* d_ws, size_t ws_size,
                              hipStream_t stream) {
    const float* X   = (const float*)d_in[0];
    const int*   cid = (const int*)d_in[1];
    const float* Wp  = (const float*)d_in[2];
    const float* Wf  = (const float*)d_in[3];
    float* out = (float*)d_out;
    const int n = in_sizes[1];

    if (ws_size >= PW_BYTES && n > STRIDE) {
        unsigned* pw = (unsigned*)d_ws;
        pack_weights<<<(PW_DWORDS + 255) / 256, 256, 0, stream>>>(Wp, Wf, pw);
        lad_ldsw16<<<NBLK, 1024, 0, stream>>>(X, cid, pw, out, n);
    } else {
        const int blocks = (n + 3) / 4;
        lad_fallback<<<blocks, 256, 0, stream>>>(X, cid, Wp, Wf, out, n);
    }
}